// Round 8
// baseline (2276.038 us; speedup 1.0000x reference)
//
#include <hip/hip_runtime.h>
#include <math.h>

#define I_DIM 1025
#define J_DIM 1024
#define K_DIM 8
#define N_ITER 10
#define EPS 1e-20f
#define REG 1e-6f
#define NBLK 512
#define MODE_CD  1
#define MODE_NMF 2
#define BAR_MAGIC 0x7F31C0DEu
#define NB_BAR 24

__device__ __forceinline__ float __frcp(float x){ return __builtin_amdgcn_rcpf(x); }

__device__ __forceinline__ float2 cmul(float2 a, float2 b){
  return make_float2(a.x*b.x - a.y*b.y, a.x*b.y + a.y*b.x);
}
__device__ __forceinline__ float2 cadd(float2 a, float2 b){
  return make_float2(a.x+b.x, a.y+b.y);
}
__device__ __forceinline__ float2 csub(float2 a, float2 b){
  return make_float2(a.x-b.x, a.y-b.y);
}
__device__ __forceinline__ float2 cconj(float2 a){ return make_float2(a.x, -a.y); }
__device__ __forceinline__ float2 cscale(float2 a, float s){ return make_float2(a.x*s, a.y*s); }
__device__ __forceinline__ float2 cdivc(float2 a, float2 d){
  float inv = 1.0f/(d.x*d.x + d.y*d.y);
  return make_float2((a.x*d.x + a.y*d.y)*inv, (a.y*d.x - a.x*d.y)*inv);
}

// ---- software grid barrier (all NBLK blocks co-resident by launch_bounds) ----
__device__ __forceinline__ void gsync(unsigned* cnt){
  __syncthreads();
  if (threadIdx.x == 0){
    __threadfence();                                   // release block's writes (agent scope)
    atomicAdd(cnt, 1u);                                // device-scope by default on global
    while (__hip_atomic_load(cnt, __ATOMIC_ACQUIRE, __HIP_MEMORY_SCOPE_AGENT) < NBLK)
      __builtin_amdgcn_s_sleep(2);
  }
  __syncthreads();
  __threadfence();                                     // acquire: no stale L1/L2 reads
}

// ---- CD(+solve+W) and/or NMF T-update for frequency bin i (4 waves, n=tid>>7) ----
__device__ __forceinline__ void cda_phase(int i, int tid, int mode,
      const float4* __restrict__ Xc4, float* __restrict__ Tw, float* __restrict__ Told,
      const float* __restrict__ Vw, float2* __restrict__ Wm,
      float (*redD)[4], float (*redT)[16], float* wsh)
{
  int n = tid >> 7, jl = tid & 127;
  float t[8];
  #pragma unroll
  for (int k=0;k<8;k++) t[k] = Tw[(size_t)(n*K_DIM+k)*I_DIM + i];

  const float* vb = Vw + (size_t)(n*K_DIM)*J_DIM + jl;
  float r_s[8] = {0,0,0,0,0,0,0,0};
  #pragma unroll
  for (int k=0;k<8;k++){
    #pragma unroll
    for (int s=0;s<8;s++) r_s[s] += t[k]*vb[k*J_DIM + 128*s];
  }
  float q_s[8];
  #pragma unroll
  for (int s=0;s<8;s++) q_s[s] = __frcp(r_s[s] + EPS);

  const float4* xb = Xc4 + (size_t)i*J_DIM + jl;
  float4 x_s[8];
  #pragma unroll
  for (int s=0;s<8;s++) x_s[s] = xb[128*s];     // coalesced

  if (mode & MODE_CD){
    float d00=0.0f, d11=0.0f, dre=0.0f, dim_=0.0f;
    #pragma unroll
    for (int s=0;s<8;s++){
      float4 x = x_s[s]; float q = q_s[s];
      d00 += (x.x*x.x + x.y*x.y)*q;
      d11 += (x.z*x.z + x.w*x.w)*q;
      dre += (x.x*x.z + x.y*x.w)*q;   // Re(x0*conj(x1))
      dim_ += (x.y*x.z - x.x*x.w)*q;  // Im(x0*conj(x1))
    }
    #pragma unroll
    for (int off=32; off>0; off>>=1){
      d00 += __shfl_down(d00,off); d11 += __shfl_down(d11,off);
      dre += __shfl_down(dre,off); dim_ += __shfl_down(dim_,off);
    }
    {
      int lane = tid&63, wv = tid>>6;
      if (lane==0){ redD[wv][0]=d00; redD[wv][1]=d11; redD[wv][2]=dre; redD[wv][3]=dim_; }
    }
    __syncthreads();
    if (tid==0){
      const float invJ = 1.0f/(float)J_DIM;
      float D[2][4];
      #pragma unroll
      for (int c=0;c<4;c++){
        D[0][c] = (redD[0][c]+redD[1][c])*invJ;
        D[1][c] = (redD[2][c]+redD[3][c])*invJ;
      }
      float2 w00 = Wm[i*4+0], w01 = Wm[i*4+1], w10 = Wm[i*4+2], w11 = Wm[i*4+3];
      #pragma unroll
      for (int nn=0;nn<2;nn++){
        float d00_ = D[nn][0] + REG, d11_ = D[nn][1] + REG;
        float2 d01 = make_float2(D[nn][2], D[nn][3]);
        float2 d10 = cconj(d01);
        float2 A00 = cadd(cscale(w00, d00_), cmul(w01, d10));
        float2 A01 = cadd(cmul(w00, d01), cscale(w01, d11_));
        float2 A10 = cadd(cscale(w10, d00_), cmul(w11, d10));
        float2 A11 = cadd(cmul(w10, d01), cscale(w11, d11_));
        float2 det = csub(cmul(A00,A11), cmul(A01,A10));
        float2 bu0, bu1;
        if (nn==0){ bu0 = A11; bu1 = make_float2(-A10.x, -A10.y); }
        else      { bu0 = make_float2(-A01.x, -A01.y); bu1 = A00; }
        float2 b0 = cdivc(bu0, det);
        float2 b1 = cdivc(bu1, det);
        float quad = d00_*(b0.x*b0.x + b0.y*b0.y) + d11_*(b1.x*b1.x + b1.y*b1.y);
        float2 u = cmul(d01, b1);
        quad += 2.0f*(b0.x*u.x + b0.y*u.y);
        float inv = 1.0f/sqrtf(quad + EPS);
        float2 wn0 = make_float2(b0.x*inv, -b0.y*inv);
        float2 wn1 = make_float2(b1.x*inv, -b1.y*inv);
        if (nn==0){ w00=wn0; w01=wn1; } else { w10=wn0; w11=wn1; }
      }
      Wm[i*4+0]=w00; Wm[i*4+1]=w01; Wm[i*4+2]=w10; Wm[i*4+3]=w11;
      wsh[0]=w00.x; wsh[1]=w00.y; wsh[2]=w01.x; wsh[3]=w01.y;
      wsh[4]=w10.x; wsh[5]=w10.y; wsh[6]=w11.x; wsh[7]=w11.y;
    }
  } else {
    if (tid < 4){ float2 w = Wm[i*4+tid]; wsh[tid*2]=w.x; wsh[tid*2+1]=w.y; }
  }
  __syncthreads();
  if (mode & MODE_NMF){
    if ((tid & 127) < 8){
      int kk = tid & 7;
      Told[(size_t)(n*K_DIM+kk)*I_DIM + i] = t[kk];
    }
    float2 w0 = make_float2(wsh[n*4+0], wsh[n*4+1]);
    float2 w1 = make_float2(wsh[n*4+2], wsh[n*4+3]);
    float p_s[8];
    #pragma unroll
    for (int s=0;s<8;s++){
      float4 x = x_s[s];
      float yre = w0.x*x.x - w0.y*x.y + w1.x*x.z - w1.y*x.w;
      float yim = w0.x*x.y + w0.y*x.x + w1.x*x.w + w1.y*x.z;
      float q = q_s[s];
      p_s[s] = (yre*yre + yim*yim)*q*q;
    }
    float aN[8], aD[8];
    #pragma unroll
    for (int k=0;k<8;k++){
      float sn = 0.0f, sd = 0.0f;
      #pragma unroll
      for (int s=0;s<8;s++){
        float v = vb[k*J_DIM + 128*s];
        sn += p_s[s]*v; sd += q_s[s]*v;
      }
      aN[k] = sn; aD[k] = sd;
    }
    #pragma unroll
    for (int k=0;k<8;k++){
      #pragma unroll
      for (int off=32; off>0; off>>=1){
        aN[k] += __shfl_down(aN[k],off);
        aD[k] += __shfl_down(aD[k],off);
      }
    }
    {
      int lane = tid&63, wv = tid>>6;
      if (lane==0){
        #pragma unroll
        for (int k=0;k<8;k++){ redT[wv][k]=aN[k]; redT[wv][k+8]=aD[k]; }
      }
    }
    __syncthreads();
    if ((tid & 127) < 8){
      int kk = tid & 7;
      int wb = (tid>>7)*2;
      float ns = redT[wb][kk]   + redT[wb+1][kk];
      float ds = redT[wb][kk+8] + redT[wb+1][kk+8];
      size_t ti = (size_t)(n*K_DIM+kk)*I_DIM + i;
      Tw[ti] = Tw[ti]*sqrtf(ns*__frcp(ds + EPS));
    }
  }
  __syncthreads();   // guard shared reuse across the block's i-loop
}

// ---- single persistent kernel: init, txpose, A0, 10x(vupd, cda), final ----
__global__ __launch_bounds__(256, 2) void k_mega(
    const float2* __restrict__ X, const float* __restrict__ T0, const float* __restrict__ V0,
    float4* __restrict__ Xc4, float4* __restrict__ XcT,
    float* __restrict__ Tw, float* __restrict__ Told, float* __restrict__ Vw,
    float2* __restrict__ Wm, float2* __restrict__ out, unsigned* __restrict__ bar)
{
  int b = blockIdx.x, tid = threadIdx.x;
  __shared__ __align__(16) char smemraw[32*33*16];
  float4 (*tile)[33] = reinterpret_cast<float4(*)[33]>(smemraw);
  float2 (*yt)[32][33] = reinterpret_cast<float2(*)[32][33]>(smemraw);
  __shared__ float redD[4][4];
  __shared__ float redT[4][16];
  __shared__ float wsh[8];
  __shared__ float redV[4][4][16];

  // ---- barrier self-init (handles 0xAA-poisoned workspace) ----
  if (tid == 0){
    if (b == 0){
      if (__hip_atomic_load(&bar[NB_BAR], __ATOMIC_RELAXED, __HIP_MEMORY_SCOPE_AGENT) != BAR_MAGIC){
        for (int s=0;s<NB_BAR;s++)
          __hip_atomic_store(&bar[s], 0u, __ATOMIC_RELAXED, __HIP_MEMORY_SCOPE_AGENT);
        __threadfence();
        __hip_atomic_store(&bar[NB_BAR], BAR_MAGIC, __ATOMIC_RELEASE, __HIP_MEMORY_SCOPE_AGENT);
      }
    } else {
      while (__hip_atomic_load(&bar[NB_BAR], __ATOMIC_ACQUIRE, __HIP_MEMORY_SCOPE_AGENT) != BAR_MAGIC)
        __builtin_amdgcn_s_sleep(2);
    }
  }
  __syncthreads();
  int bslot = 0;

  // ---- phase INIT: T -> [n][k][i], V -> [n][k][j], W = identity ----
  {
    int gtid = b*256 + tid;
    if (gtid < 2*K_DIM*I_DIM){
      int i = gtid % I_DIM; int rest = gtid / I_DIM;
      int k = rest & 7, n = rest >> 3;
      Tw[gtid] = T0[(i*K_DIM+k)*2 + n];            // T0 [I,K,M]
    }
    if (gtid < 2*K_DIM*J_DIM){
      int n = gtid/(K_DIM*J_DIM), rem = gtid%(K_DIM*J_DIM);
      int k = rem/J_DIM, j = rem%J_DIM;
      Vw[gtid] = V0[(k*J_DIM+j)*2 + n];            // V0 [K,J,M]
    }
    if (gtid < I_DIM*4){
      int rc = gtid & 3;
      Wm[gtid] = make_float2((rc==0||rc==3)?1.0f:0.0f, 0.0f);
    }
  }

  // ---- phase TXPOSE: X [M,J,I,2] -> Xc4 [I][J] and XcT [J][I] (float4) ----
  for (int tid2 = b; tid2 < 33*32; tid2 += NBLK){
    int ib = tid2 / 32, jb = tid2 % 32;
    int i0 = ib*32, j0 = jb*32;
    int tx = tid & 31, ty = tid >> 5;   // ty 0..7
    #pragma unroll
    for (int r=0;r<4;r++){
      int jl = ty + r*8; int i = i0 + tx;
      if (i < I_DIM){
        float2 a = X[(size_t)(0*J_DIM + j0 + jl)*I_DIM + i];
        float2 c = X[(size_t)(1*J_DIM + j0 + jl)*I_DIM + i];
        float4 val = make_float4(a.x, a.y, c.x, c.y);
        tile[jl][tx] = val;
        XcT[(size_t)(j0+jl)*I_DIM + i] = val;      // coalesced in i
      }
    }
    __syncthreads();
    #pragma unroll
    for (int r=0;r<4;r++){
      int il = ty + r*8; int i = i0 + il;
      if (i < I_DIM) Xc4[(size_t)i*J_DIM + j0 + tx] = tile[tx][il];
    }
    __syncthreads();
  }
  gsync(&bar[bslot++]);

  // ---- phase A0: NMF T-update of body 0 (W = identity), saves T_old ----
  for (int i = b; i < I_DIM; i += NBLK)
    cda_phase(i, tid, MODE_NMF, Xc4, Tw, Told, Vw, Wm, redD, redT, wsh);

  for (int it = 0; it < N_ITER; it++){
    gsync(&bar[bslot++]);
    // ---- phase VUPD: V-update for body `it` ----
    {
      int n = b & 1, jg = b >> 1;
      int jj = tid & 3, ii = tid >> 2;
      int j = jg*4 + jj;
      float v[8];
      #pragma unroll
      for (int k=0;k<8;k++) v[k] = Vw[(size_t)(n*K_DIM+k)*J_DIM + j];
      float aN[8] = {0,0,0,0,0,0,0,0};
      float aD[8] = {0,0,0,0,0,0,0,0};
      const float* tob = Told + (size_t)(n*K_DIM)*I_DIM;
      const float* tnb = Tw   + (size_t)(n*K_DIM)*I_DIM;
      const float4* xcb = XcT + (size_t)j*I_DIM;
      #pragma unroll 2
      for (int i=ii; i<I_DIM; i+=64){
        float to[8], tn[8];
        #pragma unroll
        for (int k=0;k<8;k++){ to[k] = tob[k*I_DIM + i]; tn[k] = tnb[k*I_DIM + i]; }
        float4 wv = *(const float4*)&Wm[i*4 + n*2];
        float4 x  = xcb[i];                        // coalesced in i
        float r = to[0]*v[0]+to[1]*v[1]+to[2]*v[2]+to[3]*v[3]
                + to[4]*v[4]+to[5]*v[5]+to[6]*v[6]+to[7]*v[7];
        float yre = wv.x*x.x - wv.y*x.y + wv.z*x.z - wv.w*x.w;
        float yim = wv.x*x.y + wv.y*x.x + wv.z*x.w + wv.w*x.z;
        float q = __frcp(r + EPS);
        float p = (yre*yre + yim*yim)*q*q;
        #pragma unroll
        for (int k=0;k<8;k++){ aN[k] += tn[k]*p; aD[k] += tn[k]*q; }
      }
      #pragma unroll
      for (int k=0;k<8;k++){
        #pragma unroll
        for (int off=32; off>=4; off>>=1){
          aN[k] += __shfl_down(aN[k],off);
          aD[k] += __shfl_down(aD[k],off);
        }
      }
      int wv_ = tid>>6, lane = tid&63;
      if (lane < 4){
        #pragma unroll
        for (int k=0;k<8;k++){ redV[wv_][lane][k]=aN[k]; redV[wv_][lane][k+8]=aD[k]; }
      }
      __syncthreads();
      if (tid < 32){
        int jj2 = tid>>3, k = tid&7;
        float num = redV[0][jj2][k]+redV[1][jj2][k]+redV[2][jj2][k]+redV[3][jj2][k];
        float den = redV[0][jj2][k+8]+redV[1][jj2][k+8]+redV[2][jj2][k+8]+redV[3][jj2][k+8];
        size_t vi = (size_t)(n*K_DIM+k)*J_DIM + jg*4 + jj2;
        Vw[vi] *= sqrtf(num*__frcp(den + EPS));
      }
      __syncthreads();
    }
    gsync(&bar[bslot++]);
    // ---- phase CDA: CD+solve (+NMF T-update unless last iter) ----
    int mode = (it < N_ITER-1) ? (MODE_CD|MODE_NMF) : MODE_CD;
    for (int i = b; i < I_DIM; i += NBLK)
      cda_phase(i, tid, mode, Xc4, Tw, Told, Vw, Wm, redD, redT, wsh);
  }
  gsync(&bar[bslot++]);

  // reset barrier slots for the next (graph-replayed) launch
  if (b == 0 && tid == 0){
    for (int s=0;s<NB_BAR;s++)
      __hip_atomic_store(&bar[s], 0u, __ATOMIC_RELAXED, __HIP_MEMORY_SCOPE_AGENT);
  }

  // ---- phase FINAL: Y = W @ X, write out [N,J,I,2] ----
  for (int tid2 = b; tid2 < 33*32; tid2 += NBLK){
    int ib = tid2 / 32, jb = tid2 % 32;
    int i0 = ib*32, j0 = jb*32;
    int tx = tid & 31, ty = tid >> 5;
    int j = j0 + tx;
    #pragma unroll
    for (int r=0;r<4;r++){
      int il = ty + r*8; int i = i0 + il;
      if (i < I_DIM){
        float4 x = Xc4[(size_t)i*J_DIM + j];
        #pragma unroll
        for (int n=0;n<2;n++){
          float2 a = Wm[i*4+n*2+0], bb = Wm[i*4+n*2+1];
          float2 y;
          y.x = a.x*x.x - a.y*x.y + bb.x*x.z - bb.y*x.w;
          y.y = a.x*x.y + a.y*x.x + bb.x*x.w + bb.y*x.z;
          yt[n][tx][il] = y;
        }
      }
    }
    __syncthreads();
    int i = i0 + tx;
    if (i < I_DIM){
      #pragma unroll
      for (int n=0;n<2;n++){
        #pragma unroll
        for (int r=0;r<4;r++){
          int jl = ty + r*8;
          out[(size_t)(n*J_DIM + j0 + jl)*I_DIM + i] = yt[n][jl][tx];
        }
      }
    }
    __syncthreads();
  }
}

extern "C" void kernel_launch(void* const* d_in, const int* in_sizes, int n_in,
                              void* d_out, int out_size, void* d_ws, size_t ws_size,
                              hipStream_t stream){
  const float2* X  = (const float2*)d_in[0];   // [M,J,I,2]
  const float*  T0 = (const float*)d_in[1];    // [I,K,M]
  const float*  V0 = (const float*)d_in[2];    // [K,J,M]

  char* ws = (char*)d_ws;
  size_t off = 0;
  auto alloc = [&](size_t bytes)->char*{
    char* p = ws + off; off += (bytes + 255) & ~(size_t)255; return p;
  };
  unsigned* bar = (unsigned*)alloc(256);
  float4* Xc4  = (float4*)alloc((size_t)I_DIM*J_DIM*sizeof(float4));
  float4* XcT  = (float4*)alloc((size_t)J_DIM*I_DIM*sizeof(float4));
  float*  Tw   = (float*) alloc((size_t)2*K_DIM*I_DIM*sizeof(float));
  float*  Told = (float*) alloc((size_t)2*K_DIM*I_DIM*sizeof(float));
  float*  Vw   = (float*) alloc((size_t)2*K_DIM*J_DIM*sizeof(float));
  float2* Wm   = (float2*)alloc((size_t)I_DIM*4*sizeof(float2));
  float2* outp = (float2*)d_out;

  k_mega<<<dim3(NBLK), dim3(256), 0, stream>>>(X, T0, V0, Xc4, XcT,
                                               Tw, Told, Vw, Wm, outp, bar);
}

// Round 9
// 466.381 us; speedup vs baseline: 4.8802x; 4.8802x over previous
//
#include <hip/hip_runtime.h>
#include <math.h>

#define I_DIM 1025
#define J_DIM 1024
#define K_DIM 8
#define N_ITER 10
#define EPS 1e-20f
#define REG 1e-6f
#define MODE_CD  1
#define MODE_NMF 2

__device__ __forceinline__ float __frcp(float x){ return __builtin_amdgcn_rcpf(x); }

__device__ __forceinline__ float2 cmul(float2 a, float2 b){
  return make_float2(a.x*b.x - a.y*b.y, a.x*b.y + a.y*b.x);
}
__device__ __forceinline__ float2 cadd(float2 a, float2 b){
  return make_float2(a.x+b.x, a.y+b.y);
}
__device__ __forceinline__ float2 csub(float2 a, float2 b){
  return make_float2(a.x-b.x, a.y-b.y);
}
__device__ __forceinline__ float2 cconj(float2 a){ return make_float2(a.x, -a.y); }
__device__ __forceinline__ float2 cscale(float2 a, float s){ return make_float2(a.x*s, a.y*s); }
__device__ __forceinline__ float2 cdivc(float2 a, float2 d){
  float inv = 1.0f/(d.x*d.x + d.y*d.y);
  return make_float2((a.x*d.x + a.y*d.y)*inv, (a.y*d.x - a.x*d.y)*inv);
}

// ---- setup: init T/V/W + transpose X -> Xc4 [i][j], XcT [j][i] ----
// grid 1056 blocks (= 33x32 tiles), 256 threads
__global__ __launch_bounds__(256) void k_setup(
    const float2* __restrict__ X, const float* __restrict__ T0, const float* __restrict__ V0,
    float4* __restrict__ Xc4, float4* __restrict__ XcT,
    float* __restrict__ Tw, float* __restrict__ Vw, float2* __restrict__ Wm){
  __shared__ float4 tile[32][33];
  int b = blockIdx.x, tid = threadIdx.x;
  // init portion
  int gtid = b*256 + tid;
  if (gtid < 2*K_DIM*I_DIM){
    int i = gtid % I_DIM; int rest = gtid / I_DIM;
    int k = rest & 7, n = rest >> 3;
    Tw[gtid] = T0[(i*K_DIM+k)*2 + n];            // T0 [I,K,M] -> [n][k][i]
  }
  if (gtid < 2*K_DIM*J_DIM){
    int n = gtid/(K_DIM*J_DIM), rem = gtid%(K_DIM*J_DIM);
    int k = rem/J_DIM, j = rem%J_DIM;
    Vw[gtid] = V0[(k*J_DIM+j)*2 + n];            // V0 [K,J,M] -> [n][k][j]
  }
  if (gtid < I_DIM*4){
    int rc = gtid & 3;
    Wm[gtid] = make_float2((rc==0||rc==3)?1.0f:0.0f, 0.0f);
  }
  // transpose tile b
  int ib = b / 32, jb = b % 32;
  int i0 = ib*32, j0 = jb*32;
  int tx = tid & 31, ty = tid >> 5;   // ty 0..7
  #pragma unroll
  for (int r=0;r<4;r++){
    int jl = ty + r*8; int i = i0 + tx;
    if (i < I_DIM){
      float2 a = X[(size_t)(0*J_DIM + j0 + jl)*I_DIM + i];
      float2 c = X[(size_t)(1*J_DIM + j0 + jl)*I_DIM + i];
      float4 val = make_float4(a.x, a.y, c.x, c.y);
      tile[jl][tx] = val;
      XcT[(size_t)(j0+jl)*I_DIM + i] = val;      // coalesced in i
    }
  }
  __syncthreads();
  #pragma unroll
  for (int r=0;r<4;r++){
    int il = ty + r*8; int i = i0 + il;
    if (i < I_DIM) Xc4[(size_t)i*J_DIM + j0 + tx] = tile[tx][il];
  }
}

// ---- fused: [CD + 2x2 solve -> W_i] then [NMF T-update for next body] ----
// X re-loaded in NMF phase (L1-hot, 16KB/block) to keep VGPRs low.
__global__ __launch_bounds__(256, 4) void k_cda(const float4* __restrict__ Xc4,
      float* __restrict__ Tw, float* __restrict__ Told, const float* __restrict__ Vw,
      float2* __restrict__ Wm, int mode){
  int i = blockIdx.x, tid = threadIdx.x;
  int n = tid >> 7, jl = tid & 127;     // waves 0,1 -> n=0; waves 2,3 -> n=1
  __shared__ float redD[4][4];
  __shared__ float redT[4][16];
  __shared__ float wsh[8];

  float t[8];
  #pragma unroll
  for (int k=0;k<8;k++) t[k] = Tw[(size_t)(n*K_DIM+k)*I_DIM + i];

  const float* vb = Vw + (size_t)(n*K_DIM)*J_DIM + jl;
  float r_s[8] = {0,0,0,0,0,0,0,0};
  #pragma unroll
  for (int k=0;k<8;k++){
    #pragma unroll
    for (int s=0;s<8;s++) r_s[s] += t[k]*vb[k*J_DIM + 128*s];
  }
  float q_s[8];
  #pragma unroll
  for (int s=0;s<8;s++) q_s[s] = __frcp(r_s[s] + EPS);

  const float4* xb = Xc4 + (size_t)i*J_DIM + jl;

  if (mode & MODE_CD){
    float d00=0.0f, d11=0.0f, dre=0.0f, dim_=0.0f;
    #pragma unroll
    for (int s=0;s<8;s++){
      float4 x = xb[128*s]; float q = q_s[s];
      d00 += (x.x*x.x + x.y*x.y)*q;
      d11 += (x.z*x.z + x.w*x.w)*q;
      dre += (x.x*x.z + x.y*x.w)*q;   // Re(x0*conj(x1))
      dim_ += (x.y*x.z - x.x*x.w)*q;  // Im(x0*conj(x1))
    }
    #pragma unroll
    for (int off=32; off>0; off>>=1){
      d00 += __shfl_down(d00,off); d11 += __shfl_down(d11,off);
      dre += __shfl_down(dre,off); dim_ += __shfl_down(dim_,off);
    }
    {
      int lane = tid&63, wv = tid>>6;
      if (lane==0){ redD[wv][0]=d00; redD[wv][1]=d11; redD[wv][2]=dre; redD[wv][3]=dim_; }
    }
    __syncthreads();
    if (tid==0){
      const float invJ = 1.0f/(float)J_DIM;
      float D[2][4];
      #pragma unroll
      for (int c=0;c<4;c++){
        D[0][c] = (redD[0][c]+redD[1][c])*invJ;
        D[1][c] = (redD[2][c]+redD[3][c])*invJ;
      }
      float2 w00 = Wm[i*4+0], w01 = Wm[i*4+1], w10 = Wm[i*4+2], w11 = Wm[i*4+3];
      #pragma unroll
      for (int nn=0;nn<2;nn++){
        float d00_ = D[nn][0] + REG, d11_ = D[nn][1] + REG;
        float2 d01 = make_float2(D[nn][2], D[nn][3]);
        float2 d10 = cconj(d01);
        float2 A00 = cadd(cscale(w00, d00_), cmul(w01, d10));
        float2 A01 = cadd(cmul(w00, d01), cscale(w01, d11_));
        float2 A10 = cadd(cscale(w10, d00_), cmul(w11, d10));
        float2 A11 = cadd(cmul(w10, d01), cscale(w11, d11_));
        float2 det = csub(cmul(A00,A11), cmul(A01,A10));
        float2 bu0, bu1;
        if (nn==0){ bu0 = A11; bu1 = make_float2(-A10.x, -A10.y); }
        else      { bu0 = make_float2(-A01.x, -A01.y); bu1 = A00; }
        float2 b0 = cdivc(bu0, det);
        float2 b1 = cdivc(bu1, det);
        float quad = d00_*(b0.x*b0.x + b0.y*b0.y) + d11_*(b1.x*b1.x + b1.y*b1.y);
        float2 u = cmul(d01, b1);
        quad += 2.0f*(b0.x*u.x + b0.y*u.y);
        float inv = 1.0f/sqrtf(quad + EPS);
        float2 wn0 = make_float2(b0.x*inv, -b0.y*inv);
        float2 wn1 = make_float2(b1.x*inv, -b1.y*inv);
        if (nn==0){ w00=wn0; w01=wn1; } else { w10=wn0; w11=wn1; }
      }
      Wm[i*4+0]=w00; Wm[i*4+1]=w01; Wm[i*4+2]=w10; Wm[i*4+3]=w11;
      wsh[0]=w00.x; wsh[1]=w00.y; wsh[2]=w01.x; wsh[3]=w01.y;
      wsh[4]=w10.x; wsh[5]=w10.y; wsh[6]=w11.x; wsh[7]=w11.y;
    }
  } else {
    if (tid < 4){ float2 w = Wm[i*4+tid]; wsh[tid*2]=w.x; wsh[tid*2+1]=w.y; }
  }
  __syncthreads();
  if (!(mode & MODE_NMF)) return;

  // save T_old for k_vupd's p,q recompute
  if ((tid & 127) < 8){
    int kk = tid & 7;
    Told[(size_t)(n*K_DIM+kk)*I_DIM + i] = t[kk];
  }

  float2 w0 = make_float2(wsh[n*4+0], wsh[n*4+1]);
  float2 w1 = make_float2(wsh[n*4+2], wsh[n*4+3]);
  float p_s[8];
  #pragma unroll
  for (int s=0;s<8;s++){
    float4 x = xb[128*s];                  // L1-hot re-read
    float yre = w0.x*x.x - w0.y*x.y + w1.x*x.z - w1.y*x.w;
    float yim = w0.x*x.y + w0.y*x.x + w1.x*x.w + w1.y*x.z;
    float q = q_s[s];
    p_s[s] = (yre*yre + yim*yim)*q*q;
  }
  float aN[8], aD[8];
  #pragma unroll
  for (int k=0;k<8;k++){
    float sn = 0.0f, sd = 0.0f;
    #pragma unroll
    for (int s=0;s<8;s++){
      float v = vb[k*J_DIM + 128*s];
      sn += p_s[s]*v; sd += q_s[s]*v;
    }
    aN[k] = sn; aD[k] = sd;
  }
  #pragma unroll
  for (int k=0;k<8;k++){
    #pragma unroll
    for (int off=32; off>0; off>>=1){
      aN[k] += __shfl_down(aN[k],off);
      aD[k] += __shfl_down(aD[k],off);
    }
  }
  {
    int lane = tid&63, wv = tid>>6;
    if (lane==0){
      #pragma unroll
      for (int k=0;k<8;k++){ redT[wv][k]=aN[k]; redT[wv][k+8]=aD[k]; }
    }
  }
  __syncthreads();
  if ((tid & 127) < 8){
    int kk = tid & 7;
    int wb = (tid>>7)*2;
    float ns = redT[wb][kk]   + redT[wb+1][kk];
    float ds = redT[wb][kk+8] + redT[wb+1][kk+8];
    size_t ti = (size_t)(n*K_DIM+kk)*I_DIM + i;
    Tw[ti] = Tw[ti]*sqrtf(ns*__frcp(ds + EPS));
  }
}

// ---- V-update: recompute p,q from (XcT, T_old, W), reduce over I, scale V ----
// grid (J/4, 2); block 256 = 64 i-lanes x 4 j. XcT: coalesced in i.
__global__ __launch_bounds__(256, 4) void k_vupd(const float4* __restrict__ XcT,
      const float* __restrict__ Tw, const float* __restrict__ Told,
      float* __restrict__ Vw, const float2* __restrict__ Wm){
  int n = blockIdx.y;
  int tid = threadIdx.x;
  int jj = tid & 3, ii = tid >> 2;
  int j = blockIdx.x*4 + jj;
  float v[8];
  #pragma unroll
  for (int k=0;k<8;k++) v[k] = Vw[(size_t)(n*K_DIM+k)*J_DIM + j];
  float aN[8] = {0,0,0,0,0,0,0,0};
  float aD[8] = {0,0,0,0,0,0,0,0};
  const float* tob = Told + (size_t)(n*K_DIM)*I_DIM;
  const float* tnb = Tw   + (size_t)(n*K_DIM)*I_DIM;
  const float4* xcb = XcT + (size_t)j*I_DIM;
  #pragma unroll 2
  for (int i=ii; i<I_DIM; i+=64){
    float to[8], tn[8];
    #pragma unroll
    for (int k=0;k<8;k++){ to[k] = tob[k*I_DIM + i]; tn[k] = tnb[k*I_DIM + i]; }
    float4 wv = *(const float4*)&Wm[i*4 + n*2];
    float4 x  = xcb[i];                        // coalesced in i
    float r = to[0]*v[0]+to[1]*v[1]+to[2]*v[2]+to[3]*v[3]
            + to[4]*v[4]+to[5]*v[5]+to[6]*v[6]+to[7]*v[7];
    float yre = wv.x*x.x - wv.y*x.y + wv.z*x.z - wv.w*x.w;
    float yim = wv.x*x.y + wv.y*x.x + wv.z*x.w + wv.w*x.z;
    float q = __frcp(r + EPS);
    float p = (yre*yre + yim*yim)*q*q;
    #pragma unroll
    for (int k=0;k<8;k++){ aN[k] += tn[k]*p; aD[k] += tn[k]*q; }
  }
  // reduce over ii within wave (lanes with same jj: strides 4)
  #pragma unroll
  for (int k=0;k<8;k++){
    #pragma unroll
    for (int off=32; off>=4; off>>=1){
      aN[k] += __shfl_down(aN[k],off);
      aD[k] += __shfl_down(aD[k],off);
    }
  }
  __shared__ float red[4][4][16];   // [wave][jj][k | k+8]
  int wv_ = tid>>6, lane = tid&63;
  if (lane < 4){
    #pragma unroll
    for (int k=0;k<8;k++){ red[wv_][lane][k]=aN[k]; red[wv_][lane][k+8]=aD[k]; }
  }
  __syncthreads();
  if (tid < 32){
    int jj2 = tid>>3, k = tid&7;
    float num = red[0][jj2][k]+red[1][jj2][k]+red[2][jj2][k]+red[3][jj2][k];
    float den = red[0][jj2][k+8]+red[1][jj2][k+8]+red[2][jj2][k+8]+red[3][jj2][k+8];
    size_t vi = (size_t)(n*K_DIM+k)*J_DIM + blockIdx.x*4 + jj2;
    Vw[vi] *= sqrtf(num*__frcp(den + EPS));
  }
}

// ---- final: Y = W @ X, write out [N,J,I,2] (transpose via LDS tile) ----
__global__ void k_final(const float4* __restrict__ Xc4, const float2* __restrict__ Wm,
                        float2* __restrict__ out){
  __shared__ float2 yt[2][32][33];
  int i0 = blockIdx.x*32, j0 = blockIdx.y*32;
  int tx = threadIdx.x, ty = threadIdx.y;
  int j = j0 + tx;
  #pragma unroll
  for (int r=0;r<4;r++){
    int il = ty + r*8; int i = i0 + il;
    if (i < I_DIM){
      float4 x = Xc4[(size_t)i*J_DIM + j];
      #pragma unroll
      for (int n=0;n<2;n++){
        float2 a = Wm[i*4+n*2+0], b = Wm[i*4+n*2+1];
        float2 y;
        y.x = a.x*x.x - a.y*x.y + b.x*x.z - b.y*x.w;
        y.y = a.x*x.y + a.y*x.x + b.x*x.w + b.y*x.z;
        yt[n][tx][il] = y;
      }
    }
  }
  __syncthreads();
  int i = i0 + tx;
  if (i < I_DIM){
    #pragma unroll
    for (int n=0;n<2;n++){
      #pragma unroll
      for (int r=0;r<4;r++){
        int jl = ty + r*8;
        out[(size_t)(n*J_DIM + j0 + jl)*I_DIM + i] = yt[n][jl][tx];
      }
    }
  }
}

extern "C" void kernel_launch(void* const* d_in, const int* in_sizes, int n_in,
                              void* d_out, int out_size, void* d_ws, size_t ws_size,
                              hipStream_t stream){
  const float2* X  = (const float2*)d_in[0];   // [M,J,I,2]
  const float*  T0 = (const float*)d_in[1];    // [I,K,M]
  const float*  V0 = (const float*)d_in[2];    // [K,J,M]

  char* ws = (char*)d_ws;
  size_t off = 0;
  auto alloc = [&](size_t bytes)->char*{
    char* p = ws + off; off += (bytes + 255) & ~(size_t)255; return p;
  };
  float4* Xc4  = (float4*)alloc((size_t)I_DIM*J_DIM*sizeof(float4));
  float4* XcT  = (float4*)alloc((size_t)J_DIM*I_DIM*sizeof(float4));
  float*  Tw   = (float*) alloc((size_t)2*K_DIM*I_DIM*sizeof(float));
  float*  Told = (float*) alloc((size_t)2*K_DIM*I_DIM*sizeof(float));
  float*  Vw   = (float*) alloc((size_t)2*K_DIM*J_DIM*sizeof(float));
  float2* Wm   = (float2*)alloc((size_t)I_DIM*4*sizeof(float2));

  k_setup<<<33*32, 256, 0, stream>>>(X, T0, V0, Xc4, XcT, Tw, Vw, Wm);
  // A0: NMF T-update of body 0 (W = identity), saves T_old
  k_cda<<<I_DIM, 256, 0, stream>>>(Xc4, Tw, Told, Vw, Wm, MODE_NMF);
  for (int it=0; it<N_ITER; it++){
    k_vupd<<<dim3(J_DIM/4, 2), 256, 0, stream>>>(XcT, Tw, Told, Vw, Wm);
    int mode = (it < N_ITER-1) ? (MODE_CD|MODE_NMF) : MODE_CD;
    k_cda<<<I_DIM, 256, 0, stream>>>(Xc4, Tw, Told, Vw, Wm, mode);
  }
  k_final<<<dim3(33,32), dim3(32,8), 0, stream>>>(Xc4, Wm, (float2*)d_out);
}

// Round 10
// 305.453 us; speedup vs baseline: 7.4514x; 1.5269x over previous
//
#include <hip/hip_runtime.h>
#include <math.h>

#define I_DIM 1025
#define J_DIM 1024
#define K_DIM 8
#define N_ITER 10
#define EPS 1e-20f
#define REG 1e-6f
#define MODE_CD  1
#define MODE_NMF 2

__device__ __forceinline__ float __frcp(float x){ return __builtin_amdgcn_rcpf(x); }

__device__ __forceinline__ float2 cmul(float2 a, float2 b){
  return make_float2(a.x*b.x - a.y*b.y, a.x*b.y + a.y*b.x);
}
__device__ __forceinline__ float2 cadd(float2 a, float2 b){
  return make_float2(a.x+b.x, a.y+b.y);
}
__device__ __forceinline__ float2 csub(float2 a, float2 b){
  return make_float2(a.x-b.x, a.y-b.y);
}
__device__ __forceinline__ float2 cconj(float2 a){ return make_float2(a.x, -a.y); }
__device__ __forceinline__ float2 cscale(float2 a, float s){ return make_float2(a.x*s, a.y*s); }
__device__ __forceinline__ float2 cdivc(float2 a, float2 d){
  float inv = 1.0f/(d.x*d.x + d.y*d.y);
  return make_float2((a.x*d.x + a.y*d.y)*inv, (a.y*d.x - a.x*d.y)*inv);
}

// ---- setup: init T/V/W + transpose X -> Xc4 [i][j], XcT [j][i] ----
__global__ __launch_bounds__(256) void k_setup(
    const float2* __restrict__ X, const float* __restrict__ T0, const float* __restrict__ V0,
    float4* __restrict__ Xc4, float4* __restrict__ XcT,
    float* __restrict__ Tw, float* __restrict__ Vw, float2* __restrict__ Wm){
  __shared__ float4 tile[32][33];
  int b = blockIdx.x, tid = threadIdx.x;
  int gtid = b*256 + tid;
  if (gtid < 2*K_DIM*I_DIM){
    int i = gtid % I_DIM; int rest = gtid / I_DIM;
    int k = rest & 7, n = rest >> 3;
    Tw[gtid] = T0[(i*K_DIM+k)*2 + n];            // T0 [I,K,M] -> [n][k][i]
  }
  if (gtid < 2*K_DIM*J_DIM){
    int n = gtid/(K_DIM*J_DIM), rem = gtid%(K_DIM*J_DIM);
    int k = rem/J_DIM, j = rem%J_DIM;
    Vw[gtid] = V0[(k*J_DIM+j)*2 + n];            // V0 [K,J,M] -> [n][k][j]
  }
  if (gtid < I_DIM*4){
    int rc = gtid & 3;
    Wm[gtid] = make_float2((rc==0||rc==3)?1.0f:0.0f, 0.0f);
  }
  int ib = b / 32, jb = b % 32;
  int i0 = ib*32, j0 = jb*32;
  int tx = tid & 31, ty = tid >> 5;   // ty 0..7
  #pragma unroll
  for (int r=0;r<4;r++){
    int jl = ty + r*8; int i = i0 + tx;
    if (i < I_DIM){
      float2 a = X[(size_t)(0*J_DIM + j0 + jl)*I_DIM + i];
      float2 c = X[(size_t)(1*J_DIM + j0 + jl)*I_DIM + i];
      float4 val = make_float4(a.x, a.y, c.x, c.y);
      tile[jl][tx] = val;
      XcT[(size_t)(j0+jl)*I_DIM + i] = val;      // coalesced in i
    }
  }
  __syncthreads();
  #pragma unroll
  for (int r=0;r<4;r++){
    int il = ty + r*8; int i = i0 + il;
    if (i < I_DIM) Xc4[(size_t)i*J_DIM + j0 + tx] = tile[tx][il];
  }
}

// ---- fused: [CD + 2x2 solve -> W_i] then [NMF T-update for next body] ----
// Default VGPR budget (no min-wave cap): x_s/r_s/q_s/p_s/acc all stay in regs.
template<int MODE>
__global__ __launch_bounds__(256) void k_cda(const float4* __restrict__ Xc4,
      float* __restrict__ Tw, float* __restrict__ Told, const float* __restrict__ Vw,
      float2* __restrict__ Wm){
  int i = blockIdx.x, tid = threadIdx.x;
  int n = tid >> 7, jl = tid & 127;     // waves 0,1 -> n=0; waves 2,3 -> n=1
  __shared__ float redD[4][4];
  __shared__ float redT[4][16];
  __shared__ float wsh[8];

  float t[8];
  #pragma unroll
  for (int k=0;k<8;k++) t[k] = Tw[(size_t)(n*K_DIM+k)*I_DIM + i];

  const float* vb = Vw + (size_t)(n*K_DIM)*J_DIM + jl;
  float r_s[8] = {0,0,0,0,0,0,0,0};
  #pragma unroll
  for (int k=0;k<8;k++){
    #pragma unroll
    for (int s=0;s<8;s++) r_s[s] += t[k]*vb[k*J_DIM + 128*s];
  }
  float q_s[8];
  #pragma unroll
  for (int s=0;s<8;s++) q_s[s] = __frcp(r_s[s] + EPS);

  const float4* xb = Xc4 + (size_t)i*J_DIM + jl;
  float4 x_s[8];
  #pragma unroll
  for (int s=0;s<8;s++) x_s[s] = xb[128*s];     // coalesced

  if (MODE & MODE_CD){
    float d00=0.0f, d11=0.0f, dre=0.0f, dim_=0.0f;
    #pragma unroll
    for (int s=0;s<8;s++){
      float4 x = x_s[s]; float q = q_s[s];
      d00 += (x.x*x.x + x.y*x.y)*q;
      d11 += (x.z*x.z + x.w*x.w)*q;
      dre += (x.x*x.z + x.y*x.w)*q;   // Re(x0*conj(x1))
      dim_ += (x.y*x.z - x.x*x.w)*q;  // Im(x0*conj(x1))
    }
    #pragma unroll
    for (int off=32; off>0; off>>=1){
      d00 += __shfl_down(d00,off); d11 += __shfl_down(d11,off);
      dre += __shfl_down(dre,off); dim_ += __shfl_down(dim_,off);
    }
    {
      int lane = tid&63, wv = tid>>6;
      if (lane==0){ redD[wv][0]=d00; redD[wv][1]=d11; redD[wv][2]=dre; redD[wv][3]=dim_; }
    }
    __syncthreads();
    if (tid==0){
      const float invJ = 1.0f/(float)J_DIM;
      float D[2][4];
      #pragma unroll
      for (int c=0;c<4;c++){
        D[0][c] = (redD[0][c]+redD[1][c])*invJ;
        D[1][c] = (redD[2][c]+redD[3][c])*invJ;
      }
      float2 w00 = Wm[i*4+0], w01 = Wm[i*4+1], w10 = Wm[i*4+2], w11 = Wm[i*4+3];
      #pragma unroll
      for (int nn=0;nn<2;nn++){
        float d00_ = D[nn][0] + REG, d11_ = D[nn][1] + REG;
        float2 d01 = make_float2(D[nn][2], D[nn][3]);
        float2 d10 = cconj(d01);
        float2 A00 = cadd(cscale(w00, d00_), cmul(w01, d10));
        float2 A01 = cadd(cmul(w00, d01), cscale(w01, d11_));
        float2 A10 = cadd(cscale(w10, d00_), cmul(w11, d10));
        float2 A11 = cadd(cmul(w10, d01), cscale(w11, d11_));
        float2 det = csub(cmul(A00,A11), cmul(A01,A10));
        float2 bu0, bu1;
        if (nn==0){ bu0 = A11; bu1 = make_float2(-A10.x, -A10.y); }
        else      { bu0 = make_float2(-A01.x, -A01.y); bu1 = A00; }
        float2 b0 = cdivc(bu0, det);
        float2 b1 = cdivc(bu1, det);
        float quad = d00_*(b0.x*b0.x + b0.y*b0.y) + d11_*(b1.x*b1.x + b1.y*b1.y);
        float2 u = cmul(d01, b1);
        quad += 2.0f*(b0.x*u.x + b0.y*u.y);
        float inv = 1.0f/sqrtf(quad + EPS);
        float2 wn0 = make_float2(b0.x*inv, -b0.y*inv);
        float2 wn1 = make_float2(b1.x*inv, -b1.y*inv);
        if (nn==0){ w00=wn0; w01=wn1; } else { w10=wn0; w11=wn1; }
      }
      Wm[i*4+0]=w00; Wm[i*4+1]=w01; Wm[i*4+2]=w10; Wm[i*4+3]=w11;
      wsh[0]=w00.x; wsh[1]=w00.y; wsh[2]=w01.x; wsh[3]=w01.y;
      wsh[4]=w10.x; wsh[5]=w10.y; wsh[6]=w11.x; wsh[7]=w11.y;
    }
  } else {
    if (tid < 4){ float2 w = Wm[i*4+tid]; wsh[tid*2]=w.x; wsh[tid*2+1]=w.y; }
  }
  __syncthreads();
  if (!(MODE & MODE_NMF)) return;

  // save T_old for k_vupd's p,q recompute
  if ((tid & 127) < 8){
    int kk = tid & 7;
    Told[(size_t)(n*K_DIM+kk)*I_DIM + i] = t[kk];
  }

  float2 w0 = make_float2(wsh[n*4+0], wsh[n*4+1]);
  float2 w1 = make_float2(wsh[n*4+2], wsh[n*4+3]);
  float p_s[8];
  #pragma unroll
  for (int s=0;s<8;s++){
    float4 x = x_s[s];
    float yre = w0.x*x.x - w0.y*x.y + w1.x*x.z - w1.y*x.w;
    float yim = w0.x*x.y + w0.y*x.x + w1.x*x.w + w1.y*x.z;
    float q = q_s[s];
    p_s[s] = (yre*yre + yim*yim)*q*q;
  }
  float aN[8], aD[8];
  #pragma unroll
  for (int k=0;k<8;k++){
    float sn = 0.0f, sd = 0.0f;
    #pragma unroll
    for (int s=0;s<8;s++){
      float v = vb[k*J_DIM + 128*s];
      sn += p_s[s]*v; sd += q_s[s]*v;
    }
    aN[k] = sn; aD[k] = sd;
  }
  #pragma unroll
  for (int k=0;k<8;k++){
    #pragma unroll
    for (int off=32; off>0; off>>=1){
      aN[k] += __shfl_down(aN[k],off);
      aD[k] += __shfl_down(aD[k],off);
    }
  }
  {
    int lane = tid&63, wv = tid>>6;
    if (lane==0){
      #pragma unroll
      for (int k=0;k<8;k++){ redT[wv][k]=aN[k]; redT[wv][k+8]=aD[k]; }
    }
  }
  __syncthreads();
  if ((tid & 127) < 8){
    int kk = tid & 7;
    int wb = (tid>>7)*2;
    float ns = redT[wb][kk]   + redT[wb+1][kk];
    float ds = redT[wb][kk+8] + redT[wb+1][kk+8];
    size_t ti = (size_t)(n*K_DIM+kk)*I_DIM + i;
    Tw[ti] = Tw[ti]*sqrtf(ns*__frcp(ds + EPS));
  }
}

// ---- V-update: recompute p,q from (XcT, T_old, W), reduce over I, scale V ----
// grid (J/4, 2); block 256 = 64 i-lanes x 4 j. XcT: coalesced in i.
__global__ __launch_bounds__(256) void k_vupd(const float4* __restrict__ XcT,
      const float* __restrict__ Tw, const float* __restrict__ Told,
      float* __restrict__ Vw, const float2* __restrict__ Wm){
  int n = blockIdx.y;
  int tid = threadIdx.x;
  int jj = tid & 3, ii = tid >> 2;
  int j = blockIdx.x*4 + jj;
  float v[8];
  #pragma unroll
  for (int k=0;k<8;k++) v[k] = Vw[(size_t)(n*K_DIM+k)*J_DIM + j];
  float aN[8] = {0,0,0,0,0,0,0,0};
  float aD[8] = {0,0,0,0,0,0,0,0};
  const float* tob = Told + (size_t)(n*K_DIM)*I_DIM;
  const float* tnb = Tw   + (size_t)(n*K_DIM)*I_DIM;
  const float4* xcb = XcT + (size_t)j*I_DIM;
  #pragma unroll 2
  for (int i=ii; i<I_DIM; i+=64){
    float to[8], tn[8];
    #pragma unroll
    for (int k=0;k<8;k++){ to[k] = tob[k*I_DIM + i]; tn[k] = tnb[k*I_DIM + i]; }
    float4 wv = *(const float4*)&Wm[i*4 + n*2];
    float4 x  = xcb[i];                        // coalesced in i
    float r = to[0]*v[0]+to[1]*v[1]+to[2]*v[2]+to[3]*v[3]
            + to[4]*v[4]+to[5]*v[5]+to[6]*v[6]+to[7]*v[7];
    float yre = wv.x*x.x - wv.y*x.y + wv.z*x.z - wv.w*x.w;
    float yim = wv.x*x.y + wv.y*x.x + wv.z*x.w + wv.w*x.z;
    float q = __frcp(r + EPS);
    float p = (yre*yre + yim*yim)*q*q;
    #pragma unroll
    for (int k=0;k<8;k++){ aN[k] += tn[k]*p; aD[k] += tn[k]*q; }
  }
  // reduce over ii within wave (lanes with same jj: strides 4)
  #pragma unroll
  for (int k=0;k<8;k++){
    #pragma unroll
    for (int off=32; off>=4; off>>=1){
      aN[k] += __shfl_down(aN[k],off);
      aD[k] += __shfl_down(aD[k],off);
    }
  }
  __shared__ float red[4][4][16];   // [wave][jj][k | k+8]
  int wv_ = tid>>6, lane = tid&63;
  if (lane < 4){
    #pragma unroll
    for (int k=0;k<8;k++){ red[wv_][lane][k]=aN[k]; red[wv_][lane][k+8]=aD[k]; }
  }
  __syncthreads();
  if (tid < 32){
    int jj2 = tid>>3, k = tid&7;
    float num = red[0][jj2][k]+red[1][jj2][k]+red[2][jj2][k]+red[3][jj2][k];
    float den = red[0][jj2][k+8]+red[1][jj2][k+8]+red[2][jj2][k+8]+red[3][jj2][k+8];
    size_t vi = (size_t)(n*K_DIM+k)*J_DIM + blockIdx.x*4 + jj2;
    Vw[vi] *= sqrtf(num*__frcp(den + EPS));
  }
}

// ---- final: Y = W @ X, write out [N,J,I,2] (transpose via LDS tile) ----
__global__ void k_final(const float4* __restrict__ Xc4, const float2* __restrict__ Wm,
                        float2* __restrict__ out){
  __shared__ float2 yt[2][32][33];
  int i0 = blockIdx.x*32, j0 = blockIdx.y*32;
  int tx = threadIdx.x, ty = threadIdx.y;
  int j = j0 + tx;
  #pragma unroll
  for (int r=0;r<4;r++){
    int il = ty + r*8; int i = i0 + il;
    if (i < I_DIM){
      float4 x = Xc4[(size_t)i*J_DIM + j];
      #pragma unroll
      for (int n=0;n<2;n++){
        float2 a = Wm[i*4+n*2+0], b = Wm[i*4+n*2+1];
        float2 y;
        y.x = a.x*x.x - a.y*x.y + b.x*x.z - b.y*x.w;
        y.y = a.x*x.y + a.y*x.x + b.x*x.w + b.y*x.z;
        yt[n][tx][il] = y;
      }
    }
  }
  __syncthreads();
  int i = i0 + tx;
  if (i < I_DIM){
    #pragma unroll
    for (int n=0;n<2;n++){
      #pragma unroll
      for (int r=0;r<4;r++){
        int jl = ty + r*8;
        out[(size_t)(n*J_DIM + j0 + jl)*I_DIM + i] = yt[n][jl][tx];
      }
    }
  }
}

extern "C" void kernel_launch(void* const* d_in, const int* in_sizes, int n_in,
                              void* d_out, int out_size, void* d_ws, size_t ws_size,
                              hipStream_t stream){
  const float2* X  = (const float2*)d_in[0];   // [M,J,I,2]
  const float*  T0 = (const float*)d_in[1];    // [I,K,M]
  const float*  V0 = (const float*)d_in[2];    // [K,J,M]

  char* ws = (char*)d_ws;
  size_t off = 0;
  auto alloc = [&](size_t bytes)->char*{
    char* p = ws + off; off += (bytes + 255) & ~(size_t)255; return p;
  };
  float4* Xc4  = (float4*)alloc((size_t)I_DIM*J_DIM*sizeof(float4));
  float4* XcT  = (float4*)alloc((size_t)J_DIM*I_DIM*sizeof(float4));
  float*  Tw   = (float*) alloc((size_t)2*K_DIM*I_DIM*sizeof(float));
  float*  Told = (float*) alloc((size_t)2*K_DIM*I_DIM*sizeof(float));
  float*  Vw   = (float*) alloc((size_t)2*K_DIM*J_DIM*sizeof(float));
  float2* Wm   = (float2*)alloc((size_t)I_DIM*4*sizeof(float2));

  k_setup<<<33*32, 256, 0, stream>>>(X, T0, V0, Xc4, XcT, Tw, Vw, Wm);
  // A0: NMF T-update of body 0 (W = identity), saves T_old
  k_cda<MODE_NMF><<<I_DIM, 256, 0, stream>>>(Xc4, Tw, Told, Vw, Wm);
  for (int it=0; it<N_ITER; it++){
    k_vupd<<<dim3(J_DIM/4, 2), 256, 0, stream>>>(XcT, Tw, Told, Vw, Wm);
    if (it < N_ITER-1)
      k_cda<MODE_CD|MODE_NMF><<<I_DIM, 256, 0, stream>>>(Xc4, Tw, Told, Vw, Wm);
    else
      k_cda<MODE_CD><<<I_DIM, 256, 0, stream>>>(Xc4, Tw, Told, Vw, Wm);
  }
  k_final<<<dim3(33,32), dim3(32,8), 0, stream>>>(Xc4, Wm, (float2*)d_out);
}